// Round 12
// baseline (3952.257 us; speedup 1.0000x reference)
//
#include <hip/hip_runtime.h>
#include <hip/hip_bf16.h>
#include <stdint.h>

#define TT 1024
#define DD 512
#define HH 512

typedef short bf16x8 __attribute__((ext_vector_type(8)));
typedef float f32x4 __attribute__((ext_vector_type(4)));
typedef unsigned long long u64;
typedef unsigned int u32;
typedef unsigned short u16;

// ---- workspace layout (bytes) ----
#define OFF_WPACK 0ull
#define SZ_WPACK  (4096ull*1024)        // 4 MiB: 2048 x-frags + 2048 h-frags, 1 KiB each
#define OFF_XS    (OFF_WPACK + SZ_WPACK) // 64 MiB: x A-frag blobs (r11 layout)
#define SZ_XS     (1024ull*4*2*8*1024)
#define OFF_HB    (OFF_XS + SZ_XS)       // [g 4][buf 4][4096 u64] tagged h = 512 KiB
#define SZ_HB     (4ull*4*4096*8)

__device__ __forceinline__ u16 f2bf(float f){
  u32 u = __builtin_bit_cast(u32, f);
  u32 r = (u + 0x7fffu + ((u >> 16) & 1u)) >> 16;   // RNE
  return (u16)r;
}

// ---- clear hbuf tags every launch (no cross-replay state) ----
__global__ void k_clear(u64* hb){
  int id = blockIdx.x * 256 + threadIdx.x;          // 65536
  hb[id] = 0x8000000000000000ull;
}

// ---- pack B-frags: family 0 = x-wave frags (Wx), family 1 = h-wave frags (Wh) ----
__global__ void k_pack_w(const float* __restrict__ Wx, const float* __restrict__ Wh,
                         u16* __restrict__ wp){
  int id = blockIdx.x * 256 + threadIdx.x;          // 262144
  int lane = id & 63;
  union { u16 v[8]; uint4 u; } pk;
  if ((id >> 17) == 0){
    // x frags: wave q<2, K-quarter of x. col = G*512+p*16+(lane&15)
    int kk = (id >> 6) & 7, G = (id >> 9) & 3, q = (id >> 11) & 1, p = (id >> 12) & 31;
    int col = G * 512 + p * 16 + (lane & 15);
    int kb  = q * 256 + kk * 32 + (lane >> 4) * 8;
#pragma unroll
    for (int j = 0; j < 8; ++j) pk.v[j] = f2bf(Wx[(kb + j) * 2048 + col]);
    long long fid = ((p * 2 + q) * 4 + G) * 8 + kk;
    *((uint4*)wp + fid * 64 + lane) = pk.u;
  } else {
    // h frags: wave hw<2 owns cols hw*8..+8, full h-K. tile0=[G0|G1], tile1=[G2|G3]
    int id2 = id & 131071;
    int tile = (id2 >> 6) & 1, kk = (id2 >> 7) & 15, hw = (id2 >> 11) & 1, p = (id2 >> 12) & 31;
    int n = lane & 15, gp = n >> 3, cloc = n & 7;
    int G = tile * 2 + gp;
    int col = G * 512 + p * 16 + hw * 8 + cloc;
    int kb  = kk * 32 + (lane >> 4) * 8;
#pragma unroll
    for (int j = 0; j < 8; ++j) pk.v[j] = f2bf(Wh[(kb + j) * 2048 + col]);
    long long fid = 2048 + ((p * 2 + hw) * 16 + kk) * 2 + tile;
    *((uint4*)wp + fid * 64 + lane) = pk.u;
  }
}

// ---- x -> per-(t,g,q,kk) M=16 A-frag blob (verified r5/r11) ----
__global__ void k_conv_x(const float* __restrict__ x, uint4* __restrict__ xs){
  int id = blockIdx.x * 256 + threadIdx.x;          // 4,194,304
  int lane = id & 63, kk = (id >> 6) & 7, q = (id >> 9) & 1, g = (id >> 10) & 3, t = id >> 12;
  int row = g * 16 + (lane & 15);
  int k   = q * 256 + kk * 32 + (lane >> 4) * 8;
  const float* src = x + ((long long)row * TT + t) * DD + k;
  union { u16 v[8]; uint4 u; } pk;
#pragma unroll
  for (int j = 0; j < 8; ++j) pk.v[j] = f2bf(src[j]);
  xs[id] = pk.u;
}

// ---- h0 -> tagged words, buf 3, tag 0xFFFFFFFF (verified r5/r11) ----
__global__ void k_conv_h0(const float* __restrict__ h0, u64* __restrict__ hb){
  int id = blockIdx.x * 256 + threadIdx.x;          // 16384
  int row = id & 15, cp = (id >> 4) & 255, g = id >> 12;
  u32 v0 = f2bf(h0[(g * 16 + row) * HH + 2 * cp]);
  u32 v1 = f2bf(h0[(g * 16 + row) * HH + 2 * cp + 1]);
  hb[((size_t)g * 4 + 3) * 4096 + cp * 16 + row] =
      (0xFFFFFFFFull << 32) | ((u64)v1 << 16) | v0;
}

// ---- persistent scan: 128 wgs (4 groups x 32) x 256 threads ----
// r12: NO barrier in the loop. x-waves (q0,q1): x K-halves -> LDS partials
// (stride-17) + LDS flag; run <=2 steps ahead (reverse flags). h-waves
// (q2,q3): N-split (8 cols each), full h-K in own accumulator; poll tagged
// h(t-1) -> 32 MFMA -> read x-partials -> gates -> publish. Self-sufficient.
__launch_bounds__(256, 1)
__global__ void k_lstm(const float* __restrict__ bias_g, float* __restrict__ out,
                       const u16* __restrict__ wp, const uint4* __restrict__ xs,
                       u64* __restrict__ hb)
{
  __shared__ float part[2][2][4 * 272];   // [buf][xq][G*272 + row*17 + col]
  __shared__ float hch[2][2][16 * 20];    // [hw][tile][n*20 + row]
  __shared__ int sflag[8];                // 0..3: xf[buf][xq]; 4..5: hf[hw]

  const int tid  = threadIdx.x;
  const int lane = tid & 63;
  const int q    = tid >> 6;
  const int w    = blockIdx.x;
  const int g    = w >> 5;
  const int p    = w & 31;
  const int khi  = lane >> 4;
  const int llo  = lane & 15;

  if (tid < 8) sflag[tid] = -1;
  __syncthreads();

  const bf16x8* wpf = (const bf16x8*)wp;

  if (q < 2){
    // ---------------- x-wave: throughput producer of x-partials ----------------
    bf16x8 bfx[4][8];
#pragma unroll
    for (int G = 0; G < 4; ++G)
#pragma unroll
      for (int kk = 0; kk < 8; ++kk)
        bfx[G][kk] = wpf[(size_t)(((p * 2 + q) * 4 + G) * 8 + kk) * 64 + lane];

    for (int t = 0; t < TT; ++t){
      const int buf = t & 1;
      if (t >= 2){
        for (;;){
          int a = __hip_atomic_load(&sflag[4], __ATOMIC_RELAXED, __HIP_MEMORY_SCOPE_WORKGROUP);
          int b2 = __hip_atomic_load(&sflag[5], __ATOMIC_RELAXED, __HIP_MEMORY_SCOPE_WORKGROUP);
          if (a >= t - 2 && b2 >= t - 2) break;
        }
      }
      const uint4* xb = xs + ((((size_t)t * 4 + g) * 2 + q) * 8) * 64 + lane;
      f32x4 acc[4];
#pragma unroll
      for (int G = 0; G < 4; ++G) acc[G] = (f32x4){0.f, 0.f, 0.f, 0.f};
#pragma unroll
      for (int kk = 0; kk < 8; ++kk){
        bf16x8 av = __builtin_bit_cast(bf16x8, xb[kk * 64]);
#pragma unroll
        for (int G = 0; G < 4; ++G)
          acc[G] = __builtin_amdgcn_mfma_f32_16x16x32_bf16(av, bfx[G][kk], acc[G], 0, 0, 0);
      }
      float* pp = &part[buf][q][0];
#pragma unroll
      for (int G = 0; G < 4; ++G)
#pragma unroll
        for (int reg = 0; reg < 4; ++reg)
          pp[G * 272 + (khi * 4 + reg) * 17 + llo] = acc[G][reg];
      asm volatile("s_waitcnt lgkmcnt(0)" ::: "memory");
      __hip_atomic_store(&sflag[buf * 2 + q], t, __ATOMIC_RELAXED, __HIP_MEMORY_SCOPE_WORKGROUP);
    }
  } else {
    // ---------------- h-wave: owns 8 cols, full h-K, self-publishes ----------------
    const int hw = q - 2;
    bf16x8 bfh[2][16];
#pragma unroll
    for (int tile = 0; tile < 2; ++tile)
#pragma unroll
      for (int kk = 0; kk < 16; ++kk)
        bfh[tile][kk] = wpf[(size_t)(2048 + ((p * 2 + hw) * 16 + kk) * 2 + tile) * 64 + lane];

    const int r   = lane >> 2;         // batch row 0..15
    const int cp4 = lane & 3;          // col pair within own 8 cols
    const int cc0 = 2 * cp4;           // tile-local col (0..7) of element e=0
    const int cg0 = hw * 8 + cc0;      // wg-local col (0..15)
    float bia[2][4];
#pragma unroll
    for (int e = 0; e < 2; ++e)
#pragma unroll
      for (int G = 0; G < 4; ++G)
        bia[e][G] = bias_g[G * 512 + p * 16 + cg0 + e];
    float cs[2] = {0.f, 0.f};

    u64* gb = hb + (size_t)g * 4 * 4096;
    const int row   = lane & 15;
    const int swidx = (p * 8 + hw * 4 + cp4) * 16 + r;
    float* outp = out + ((size_t)(g * 16 + r) * TT) * HH + p * 16 + cg0;

    for (int t = 0; t < TT; ++t){
      const int buf = t & 1;
      // poll full tagged h(t-1): 64 words, non-divergent reload-all
      const u64* bb = gb + (size_t)((t + 3) & 3) * 4096;
      const u32 tg = (u32)(t - 1);
      u64 wv[64];
      for (;;){
#pragma unroll
        for (int kk = 0; kk < 16; ++kk)
#pragma unroll
          for (int jj = 0; jj < 4; ++jj)
            wv[kk * 4 + jj] = __hip_atomic_load(bb + kk * 256 + khi * 64 + jj * 16 + row,
                                                __ATOMIC_RELAXED, __HIP_MEMORY_SCOPE_AGENT);
        bool ok = true;
#pragma unroll
        for (int j = 0; j < 64; ++j) ok &= ((u32)(wv[j] >> 32) == tg);
        if (__all(ok)) break;
      }
      asm volatile("" ::: "memory");

      // full-K h MFMA into 2 packed N-tiles
      f32x4 a0 = (f32x4){0.f, 0.f, 0.f, 0.f};
      f32x4 a1 = (f32x4){0.f, 0.f, 0.f, 0.f};
#pragma unroll
      for (int kk = 0; kk < 16; ++kk){
        union { u32 d[4]; bf16x8 v; } af;
#pragma unroll
        for (int jj = 0; jj < 4; ++jj) af.d[jj] = (u32)wv[kk * 4 + jj];
        a0 = __builtin_amdgcn_mfma_f32_16x16x32_bf16(af.v, bfh[0][kk], a0, 0, 0, 0);
        a1 = __builtin_amdgcn_mfma_f32_16x16x32_bf16(af.v, bfh[1][kk], a1, 0, 0, 0);
      }

      // wave-local transpose of acc into hch
      {
        float* hc0 = &hch[hw][0][0];
        float* hc1 = &hch[hw][1][0];
#pragma unroll
        for (int reg = 0; reg < 4; ++reg){
          hc0[llo * 20 + khi * 4 + reg] = a0[reg];
          hc1[llo * 20 + khi * 4 + reg] = a1[reg];
        }
      }
      // wait x-partials of step t (normally already set)
      for (;;){
        int f0 = __hip_atomic_load(&sflag[buf * 2],     __ATOMIC_RELAXED, __HIP_MEMORY_SCOPE_WORKGROUP);
        int f1 = __hip_atomic_load(&sflag[buf * 2 + 1], __ATOMIC_RELAXED, __HIP_MEMORY_SCOPE_WORKGROUP);
        if (f0 >= t && f1 >= t) break;
      }
      asm volatile("s_waitcnt lgkmcnt(0)" ::: "memory");
      __builtin_amdgcn_sched_barrier(0);

      // gate pre-activations: own acc (via hch) + x-partials + bias
      const float* p0 = &part[buf][0][0];
      const float* p1 = &part[buf][1][0];
      float aG[2][4];
#pragma unroll
      for (int e = 0; e < 2; ++e)
#pragma unroll
        for (int G = 0; G < 4; ++G)
          aG[e][G] = p0[G * 272 + r * 17 + cg0 + e] + p1[G * 272 + r * 17 + cg0 + e]
                   + hch[hw][G >> 1][((G & 1) * 8 + cc0 + e) * 20 + r] + bia[e][G];
      asm volatile("s_waitcnt lgkmcnt(0)" ::: "memory");   // part reads complete
      __hip_atomic_store(&sflag[4 + hw], t, __ATOMIC_RELAXED, __HIP_MEMORY_SCOPE_WORKGROUP);

      float hv[2]; u32 h16[2];
#pragma unroll
      for (int e = 0; e < 2; ++e){
        float gi = 1.f / (1.f + __expf(-aG[e][0]));
        float gf = 1.f / (1.f + __expf(-aG[e][1]));
        float go = 1.f / (1.f + __expf(-aG[e][2]));
        float e2 = __expf(-2.f * fabsf(aG[e][3]));
        float gg = __builtin_copysignf((1.f - e2) / (1.f + e2), aG[e][3]);
        float c  = gf * cs[e] + gi * gg;
        cs[e] = c;
        float ec = __expf(-2.f * fabsf(c));
        float th = __builtin_copysignf((1.f - ec) / (1.f + ec), c);
        hv[e] = go * th;
        h16[e] = f2bf(hv[e]);
      }
      // publish first (critical path), then output
      u64 word = ((u64)(u32)t << 32) | ((u64)h16[1] << 16) | (u64)h16[0];
      __hip_atomic_store(gb + (size_t)(t & 3) * 4096 + swidx, word,
                         __ATOMIC_RELAXED, __HIP_MEMORY_SCOPE_AGENT);
      *(float2*)(outp + (size_t)t * HH) = make_float2(hv[0], hv[1]);
    }
  }
}

extern "C" void kernel_launch(void* const* d_in, const int* in_sizes, int n_in,
                              void* d_out, int out_size, void* d_ws, size_t ws_size,
                              hipStream_t stream){
  const float* x  = (const float*)d_in[0];
  const float* h0 = (const float*)d_in[1];
  const float* Wx = (const float*)d_in[2];
  const float* Wh = (const float*)d_in[3];
  const float* b  = (const float*)d_in[4];
  float* out = (float*)d_out;

  unsigned char* ws = (unsigned char*)d_ws;
  u16*   wp = (u16*)(ws + OFF_WPACK);
  uint4* xs = (uint4*)(ws + OFF_XS);
  u64*   hbp = (u64*)(ws + OFF_HB);

  hipLaunchKernelGGL(k_clear,   dim3(256),   dim3(256), 0, stream, hbp);
  hipLaunchKernelGGL(k_pack_w,  dim3(1024),  dim3(256), 0, stream, Wx, Wh, wp);
  hipLaunchKernelGGL(k_conv_x,  dim3(16384), dim3(256), 0, stream, x, xs);
  hipLaunchKernelGGL(k_conv_h0, dim3(64),    dim3(256), 0, stream, h0, hbp);
  hipLaunchKernelGGL(k_lstm,    dim3(128),   dim3(256), 0, stream, b, out, wp, xs, hbp);
}

// Round 13
// 3031.917 us; speedup vs baseline: 1.3036x; 1.3036x over previous
//
#include <hip/hip_runtime.h>
#include <hip/hip_bf16.h>
#include <stdint.h>

#define TT 1024
#define DD 512
#define HH 512

typedef short bf16x8 __attribute__((ext_vector_type(8)));
typedef float f32x4 __attribute__((ext_vector_type(4)));
typedef unsigned long long u64;
typedef unsigned int u32;
typedef unsigned short u16;

// ---- workspace layout (bytes) ---- (identical to r5/r11)
#define OFF_WPACK 0ull
#define SZ_WPACK  (32ull*4*4*8*1024)
#define OFF_XS    (OFF_WPACK + SZ_WPACK)
#define SZ_XS     (1024ull*4*2*8*1024)
#define OFF_HB    (OFF_XS + SZ_XS)
#define SZ_HB     (4ull*4*4096*8)

__device__ __forceinline__ u16 f2bf(float f){
  u32 u = __builtin_bit_cast(u32, f);
  u32 r = (u + 0x7fffu + ((u >> 16) & 1u)) >> 16;   // RNE
  return (u16)r;
}

// ---- clear all hbuf tags every launch (no cross-replay state) ----
__global__ void k_clear(u64* hb){
  int id = blockIdx.x * 256 + threadIdx.x;          // 65536
  hb[id] = 0x8000000000000000ull;
}

// ---- pack Wcat=[Wx;Wh] into B-frags (verified r5/r11) ----
__global__ void k_pack_w(const float* __restrict__ Wx, const float* __restrict__ Wh,
                         u16* __restrict__ wp){
  int id = blockIdx.x * 256 + threadIdx.x;          // 262144
  int lane = id & 63;
  int kk = (id >> 6) & 7, G = (id >> 9) & 3, q = (id >> 11) & 3, p = id >> 13;
  int col = G * 512 + p * 16 + (lane & 15);
  int kb  = q * 256 + kk * 32 + (lane >> 4) * 8;
  union { u16 v[8]; uint4 u; } pk;
#pragma unroll
  for (int j = 0; j < 8; ++j){
    int k = kb + j;
    float f = (k < 512) ? Wx[k * 2048 + col] : Wh[(k - 512) * 2048 + col];
    pk.v[j] = f2bf(f);
  }
  long long fid = ((p * 4 + q) * 4 + G) * 8 + kk;
  *((uint4*)wp + fid * 64 + lane) = pk.u;
}

// ---- x -> per-(t,g,q,kk) M=16 A-frag blob (verified r5/r11) ----
__global__ void k_conv_x(const float* __restrict__ x, uint4* __restrict__ xs){
  int id = blockIdx.x * 256 + threadIdx.x;          // 4,194,304
  int lane = id & 63, kk = (id >> 6) & 7, q = (id >> 9) & 1, g = (id >> 10) & 3, t = id >> 12;
  int row = g * 16 + (lane & 15);
  int k   = q * 256 + kk * 32 + (lane >> 4) * 8;
  const float* src = x + ((long long)row * TT + t) * DD + k;
  union { u16 v[8]; uint4 u; } pk;
#pragma unroll
  for (int j = 0; j < 8; ++j) pk.v[j] = f2bf(src[j]);
  xs[id] = pk.u;
}

// ---- h0 -> tagged words, buf 3, tag 0xFFFFFFFF (verified r5/r11) ----
__global__ void k_conv_h0(const float* __restrict__ h0, u64* __restrict__ hb){
  int id = blockIdx.x * 256 + threadIdx.x;          // 16384
  int row = id & 15, cp = (id >> 4) & 255, g = id >> 12;
  u32 v0 = f2bf(h0[(g * 16 + row) * HH + 2 * cp]);
  u32 v1 = f2bf(h0[(g * 16 + row) * HH + 2 * cp + 1]);
  hb[((size_t)g * 4 + 3) * 4096 + cp * 16 + row] =
      (0xFFFFFFFFull << 32) | ((u64)v1 << 16) | v0;
}

// ---- persistent scan: 128 wgs (4 groups x 32) x 256 threads ----
// r13 = r11 with ONE change: publish via fire-and-forget atomic exchange
// (RMW executes at the MALL coherence point -> prompt visibility; result
// discarded so no sc0/no wait). Everything else byte-identical to r11.
__launch_bounds__(256, 1)
__global__ void k_lstm(const float* __restrict__ bias_g, float* __restrict__ out,
                       const u16* __restrict__ wp, const uint4* __restrict__ xs,
                       u64* __restrict__ hbufs)
{
  __shared__ float part[2][4096];    // [buf][q*1024 + G*256 + row*16 + col]

  const int tid  = threadIdx.x;
  const int lane = tid & 63;
  const int q    = tid >> 6;
  const int w    = blockIdx.x;
  const int g    = w >> 5;
  const int p    = w & 31;
  const int khi  = lane >> 4;
  const int llo  = lane & 15;

  // persistent B fragments: 32 frags = 128 VGPRs
  bf16x8 bfrag[4][8];
  {
    const bf16x8* wpf = (const bf16x8*)wp;
#pragma unroll
    for (int G = 0; G < 4; ++G)
#pragma unroll
      for (int kk = 0; kk < 8; ++kk)
        bfrag[G][kk] = wpf[(((p * 4 + q) * 4 + G) * 8 + kk) * 64 + lane];
  }

  // gate mapping (x-waves, tid<128): thread -> (row r, col pair 2cp,2cp+1)
  const int tt = tid & 127;
  const int r  = tt >> 3;            // 0..15
  const int cp = tt & 7;             // 0..7
  float bia[4][2];
#pragma unroll
  for (int G = 0; G < 4; ++G)
#pragma unroll
    for (int e = 0; e < 2; ++e)
      bia[G][e] = bias_g[G * 512 + p * 16 + 2 * cp + e];
  float cs[2] = {0.f, 0.f};

  u64* gb = hbufs + (size_t)g * 4 * 4096;
  const int wbase = (((q & 1) * 128 + khi * 4) * 16) + llo;   // consumer (r5)
  const int swidx = (p * 8 + cp) * 16 + r;                    // producer word idx
  float* outp = out + ((size_t)(g * 16 + r) * TT) * HH + p * 16 + 2 * cp;

  const bool is_h = (q >= 2);

  for (int t = 0; t < TT; ++t){
    f32x4 acc[4];
#pragma unroll
    for (int n = 0; n < 4; ++n) acc[n] = (f32x4){0.f, 0.f, 0.f, 0.f};

    if (!is_h){
      // x K-half: plain cached frag loads, never blocks on recurrence
      const uint4* xb = xs + ((((size_t)t * 4 + g) * 2 + q) * 8) * 64 + lane;
#pragma unroll
      for (int kk = 0; kk < 8; ++kk){
        bf16x8 av = __builtin_bit_cast(bf16x8, xb[kk * 64]);
#pragma unroll
        for (int n = 0; n < 4; ++n)
          acc[n] = __builtin_amdgcn_mfma_f32_16x16x32_bf16(av, bfrag[n][kk], acc[n], 0, 0, 0);
      }
    } else {
      // h K-half: non-divergent reload-all poll of tagged h(t-1)  (r5 verbatim)
      const u64* bb = gb + (size_t)((t + 3) & 3) * 4096;
      const u32 tg = (u32)(t - 1);
      u64 wv[32];
      for (;;){
#pragma unroll
        for (int j = 0; j < 32; ++j){
          int kk = j >> 2, jj = j & 3;
          wv[j] = __hip_atomic_load(bb + wbase + kk * 256 + jj * 16,
                                    __ATOMIC_RELAXED, __HIP_MEMORY_SCOPE_AGENT);
        }
        bool ok = true;
#pragma unroll
        for (int j = 0; j < 32; ++j) ok &= ((u32)(wv[j] >> 32) == tg);
        if (__all(ok)) break;
      }
      asm volatile("" ::: "memory");
#pragma unroll
      for (int kk = 0; kk < 8; ++kk){
        union { u32 d[4]; bf16x8 v; } af;
#pragma unroll
        for (int jj = 0; jj < 4; ++jj) af.d[jj] = (u32)wv[kk * 4 + jj];
#pragma unroll
        for (int n = 0; n < 4; ++n)
          acc[n] = __builtin_amdgcn_mfma_f32_16x16x32_bf16(af.v, bfrag[n][kk], acc[n], 0, 0, 0);
      }
    }

    // K-partials to double-buffered LDS (r5 verbatim)
    float* pb = &part[t & 1][0];
#pragma unroll
    for (int n = 0; n < 4; ++n)
#pragma unroll
      for (int rr = 0; rr < 4; ++rr)
        pb[q * 1024 + n * 256 + (khi * 4 + rr) * 16 + llo] = acc[n][rr];
    __syncthreads();   // single barrier per step

    // gates + publish on x-waves only; h-waves loop straight back to polling
    if (tid < 128){
      const float* pr = pb + r * 16 + 2 * cp;
      float hv[2]; u32 hb16[2];
#pragma unroll
      for (int e = 0; e < 2; ++e){
        float aG[4];
#pragma unroll
        for (int G = 0; G < 4; ++G)
          aG[G] = pr[G * 256 + e] + pr[1024 + G * 256 + e]
                + pr[2048 + G * 256 + e] + pr[3072 + G * 256 + e] + bia[G][e];
        float gi = 1.f / (1.f + __expf(-aG[0]));
        float gf = 1.f / (1.f + __expf(-aG[1]));
        float go = 1.f / (1.f + __expf(-aG[2]));
        float e2 = __expf(-2.f * fabsf(aG[3]));
        float gg = __builtin_copysignf((1.f - e2) / (1.f + e2), aG[3]);
        float c  = gf * cs[e] + gi * gg;
        cs[e] = c;
        float ec = __expf(-2.f * fabsf(c));
        float th = __builtin_copysignf((1.f - ec) / (1.f + ec), c);
        hv[e] = go * th;
        hb16[e] = f2bf(hv[e]);
      }
      // publish first (critical path): fire-and-forget swap executes at MALL
      u64 word = ((u64)(u32)t << 32) | ((u64)hb16[1] << 16) | (u64)hb16[0];
      (void)__hip_atomic_exchange(gb + (size_t)(t & 3) * 4096 + swidx, word,
                                  __ATOMIC_RELAXED, __HIP_MEMORY_SCOPE_AGENT);
      // output off the critical path
      *(float2*)(outp + (size_t)t * HH) = make_float2(hv[0], hv[1]);
    }
  }
}

extern "C" void kernel_launch(void* const* d_in, const int* in_sizes, int n_in,
                              void* d_out, int out_size, void* d_ws, size_t ws_size,
                              hipStream_t stream){
  const float* x  = (const float*)d_in[0];
  const float* h0 = (const float*)d_in[1];
  const float* Wx = (const float*)d_in[2];
  const float* Wh = (const float*)d_in[3];
  const float* b  = (const float*)d_in[4];
  float* out = (float*)d_out;

  unsigned char* ws = (unsigned char*)d_ws;
  u16*   wp = (u16*)(ws + OFF_WPACK);
  uint4* xs = (uint4*)(ws + OFF_XS);
  u64*   hb = (u64*)(ws + OFF_HB);

  hipLaunchKernelGGL(k_clear,   dim3(256),   dim3(256), 0, stream, hb);
  hipLaunchKernelGGL(k_pack_w,  dim3(1024),  dim3(256), 0, stream, Wx, Wh, wp);
  hipLaunchKernelGGL(k_conv_x,  dim3(16384), dim3(256), 0, stream, x, xs);
  hipLaunchKernelGGL(k_conv_h0, dim3(64),    dim3(256), 0, stream, h0, hb);
  hipLaunchKernelGGL(k_lstm,    dim3(128),   dim3(256), 0, stream, b, out, wp, xs, hb);
}

// Round 14
// 2936.794 us; speedup vs baseline: 1.3458x; 1.0324x over previous
//
#include <hip/hip_runtime.h>
#include <hip/hip_bf16.h>
#include <stdint.h>

#define TT 1024
#define DD 512
#define HH 512

typedef short bf16x8 __attribute__((ext_vector_type(8)));
typedef float f32x4 __attribute__((ext_vector_type(4)));
typedef unsigned long long u64;
typedef unsigned int u32;
typedef unsigned short u16;

// ---- workspace layout (bytes) ---- (identical to r5/r11)
#define OFF_WPACK 0ull
#define SZ_WPACK  (32ull*4*4*8*1024)
#define OFF_XS    (OFF_WPACK + SZ_WPACK)
#define SZ_XS     (1024ull*4*2*8*1024)
#define OFF_HB    (OFF_XS + SZ_XS)
#define SZ_HB     (4ull*4*4096*8)

__device__ __forceinline__ u16 f2bf(float f){
  u32 u = __builtin_bit_cast(u32, f);
  u32 r = (u + 0x7fffu + ((u >> 16) & 1u)) >> 16;   // RNE
  return (u16)r;
}

// ---- clear all hbuf tags every launch (no cross-replay state) ----
__global__ void k_clear(u64* hb){
  int id = blockIdx.x * 256 + threadIdx.x;          // 65536
  hb[id] = 0x8000000000000000ull;
}

// ---- pack Wcat=[Wx;Wh] into B-frags (verified r5/r11) ----
__global__ void k_pack_w(const float* __restrict__ Wx, const float* __restrict__ Wh,
                         u16* __restrict__ wp){
  int id = blockIdx.x * 256 + threadIdx.x;          // 262144
  int lane = id & 63;
  int kk = (id >> 6) & 7, G = (id >> 9) & 3, q = (id >> 11) & 3, p = id >> 13;
  int col = G * 512 + p * 16 + (lane & 15);
  int kb  = q * 256 + kk * 32 + (lane >> 4) * 8;
  union { u16 v[8]; uint4 u; } pk;
#pragma unroll
  for (int j = 0; j < 8; ++j){
    int k = kb + j;
    float f = (k < 512) ? Wx[k * 2048 + col] : Wh[(k - 512) * 2048 + col];
    pk.v[j] = f2bf(f);
  }
  long long fid = ((p * 4 + q) * 4 + G) * 8 + kk;
  *((uint4*)wp + fid * 64 + lane) = pk.u;
}

// ---- x -> per-(t,g,q,kk) M=16 A-frag blob (verified r5/r11) ----
__global__ void k_conv_x(const float* __restrict__ x, uint4* __restrict__ xs){
  int id = blockIdx.x * 256 + threadIdx.x;          // 4,194,304
  int lane = id & 63, kk = (id >> 6) & 7, q = (id >> 9) & 1, g = (id >> 10) & 3, t = id >> 12;
  int row = g * 16 + (lane & 15);
  int k   = q * 256 + kk * 32 + (lane >> 4) * 8;
  const float* src = x + ((long long)row * TT + t) * DD + k;
  union { u16 v[8]; uint4 u; } pk;
#pragma unroll
  for (int j = 0; j < 8; ++j) pk.v[j] = f2bf(src[j]);
  xs[id] = pk.u;
}

// ---- h0 -> tagged words, buf 3, tag 0xFFFFFFFF (verified r5/r11) ----
__global__ void k_conv_h0(const float* __restrict__ h0, u64* __restrict__ hb){
  int id = blockIdx.x * 256 + threadIdx.x;          // 16384
  int row = id & 15, cp = (id >> 4) & 255, g = id >> 12;
  u32 v0 = f2bf(h0[(g * 16 + row) * HH + 2 * cp]);
  u32 v1 = f2bf(h0[(g * 16 + row) * HH + 2 * cp + 1]);
  hb[((size_t)g * 4 + 3) * 4096 + cp * 16 + row] =
      (0xFFFFFFFFull << 32) | ((u64)v1 << 16) | v0;
}

// ---- persistent scan: 128 wgs (4 groups x 32) x 256 threads ----
// r14 = r11 structure with the per-step barrier replaced by monotone LDS
// flags; gates+publish on h-waves straight out of the MFMA pipeline.
// Polls (32-word K-split), MALL buffers, gate addition ORDER all r11-exact.
// Flags: xf[buf][xq] (x partials ready), hp[buf][hw] (h partials ready),
// gd[hw] (h-wave finished reading buf) -- acyclic, 2-step slack.
__launch_bounds__(256, 1)
__global__ void k_lstm(const float* __restrict__ bias_g, float* __restrict__ out,
                       const u16* __restrict__ wp, const uint4* __restrict__ xs,
                       u64* __restrict__ hbufs)
{
  __shared__ float xpart[2][2][1088];   // [buf][xq][G*272 + row*17 + col]
  __shared__ float hpart[2][2][1088];   // [buf][hw][G*272 + row*17 + col]
  __shared__ int sflag[12];             // 0..3 xf[buf*2+xq]; 4..7 hp[4+buf*2+hw]; 8..9 gd[8+hw]

  const int tid  = threadIdx.x;
  const int lane = tid & 63;
  const int q    = tid >> 6;
  const int w    = blockIdx.x;
  const int g    = w >> 5;
  const int p    = w & 31;
  const int khi  = lane >> 4;
  const int llo  = lane & 15;

  if (tid < 12) sflag[tid] = -1;
  __syncthreads();   // startup only

  // persistent B fragments: 32 frags = 128 VGPRs
  bf16x8 bfrag[4][8];
  {
    const bf16x8* wpf = (const bf16x8*)wp;
#pragma unroll
    for (int G = 0; G < 4; ++G)
#pragma unroll
      for (int kk = 0; kk < 8; ++kk)
        bfrag[G][kk] = wpf[(((p * 4 + q) * 4 + G) * 8 + kk) * 64 + lane];
  }

  u64* gb = hbufs + (size_t)g * 4 * 4096;

  if (q < 2){
    // ------------- x-wave: free-runs <=2 ahead, partials producer -------------
    for (int t = 0; t < TT; ++t){
      const int buf = t & 1;
      // issue x-frag loads first (HBM latency overlaps the gd wait)
      const uint4* xb = xs + ((((size_t)t * 4 + g) * 2 + q) * 8) * 64 + lane;
      uint4 xf8[8];
#pragma unroll
      for (int kk = 0; kk < 8; ++kk) xf8[kk] = xb[kk * 64];
      // buffer release: both h-waves done reading xpart[buf] (step t-2)
      for (;;){
        int g0 = __hip_atomic_load(&sflag[8], __ATOMIC_RELAXED, __HIP_MEMORY_SCOPE_WORKGROUP);
        int g1 = __hip_atomic_load(&sflag[9], __ATOMIC_RELAXED, __HIP_MEMORY_SCOPE_WORKGROUP);
        if (g0 >= t - 2 && g1 >= t - 2) break;
      }
      f32x4 acc[4];
#pragma unroll
      for (int G = 0; G < 4; ++G) acc[G] = (f32x4){0.f, 0.f, 0.f, 0.f};
#pragma unroll
      for (int kk = 0; kk < 8; ++kk){
        bf16x8 av = __builtin_bit_cast(bf16x8, xf8[kk]);
#pragma unroll
        for (int G = 0; G < 4; ++G)
          acc[G] = __builtin_amdgcn_mfma_f32_16x16x32_bf16(av, bfrag[G][kk], acc[G], 0, 0, 0);
      }
      float* pp = &xpart[buf][q][0];
#pragma unroll
      for (int G = 0; G < 4; ++G)
#pragma unroll
        for (int reg = 0; reg < 4; ++reg)
          pp[G * 272 + (khi * 4 + reg) * 17 + llo] = acc[G][reg];
      asm volatile("s_waitcnt lgkmcnt(0)" ::: "memory");
      __hip_atomic_store(&sflag[buf * 2 + q], t, __ATOMIC_RELAXED, __HIP_MEMORY_SCOPE_WORKGROUP);
    }
  } else {
    // ------------- h-wave: poll -> MFMA -> combine -> gates -> publish -------------
    const int hw = q - 2;
    const int wbase = ((hw * 128 + khi * 4) * 16) + llo;    // consumer (r11 verbatim)
    const int cp4 = khi;            // own col pair 0..3 within 8 cols
    const int r   = llo;            // batch row
    const int c0  = hw * 8 + 2 * cp4;                       // wg-local col of e=0
    float bia[2][4];
#pragma unroll
    for (int e = 0; e < 2; ++e)
#pragma unroll
      for (int G = 0; G < 4; ++G)
        bia[e][G] = bias_g[G * 512 + p * 16 + c0 + e];
    float cs[2] = {0.f, 0.f};
    const int swidx = (p * 8 + hw * 4 + cp4) * 16 + r;
    float* outp = out + ((size_t)(g * 16 + r) * TT) * HH + p * 16 + c0;
    float pend0 = 0.f, pend1 = 0.f;

    for (int t = 0; t < TT; ++t){
      const int buf = t & 1;
      // poll tagged h(t-1): 32 words, non-divergent reload-all (r11 verbatim)
      const u64* bb = gb + (size_t)((t + 3) & 3) * 4096;
      const u32 tg = (u32)(t - 1);
      u64 wv[32];
      for (;;){
#pragma unroll
        for (int j = 0; j < 32; ++j){
          int kk = j >> 2, jj = j & 3;
          wv[j] = __hip_atomic_load(bb + wbase + kk * 256 + jj * 16,
                                    __ATOMIC_RELAXED, __HIP_MEMORY_SCOPE_AGENT);
        }
        bool ok = true;
#pragma unroll
        for (int j = 0; j < 32; ++j) ok &= ((u32)(wv[j] >> 32) == tg);
        if (__all(ok)) break;
      }
      asm volatile("" ::: "memory");
      // deferred out store of step t-1 (its HBM ack overlaps this step's MFMA)
      if (t > 0) *(float2*)(outp + (size_t)(t - 1) * HH) = make_float2(pend0, pend1);

      f32x4 acc[4];
#pragma unroll
      for (int n = 0; n < 4; ++n) acc[n] = (f32x4){0.f, 0.f, 0.f, 0.f};
#pragma unroll
      for (int kk = 0; kk < 8; ++kk){
        union { u32 d[4]; bf16x8 v; } af;
#pragma unroll
        for (int jj = 0; jj < 4; ++jj) af.d[jj] = (u32)wv[kk * 4 + jj];
#pragma unroll
        for (int n = 0; n < 4; ++n)
          acc[n] = __builtin_amdgcn_mfma_f32_16x16x32_bf16(af.v, bfrag[n][kk], acc[n], 0, 0, 0);
      }
      // buffer release by the OTHER h-wave (own reads of buf were at t-2, program order)
      for (;;){
        int go = __hip_atomic_load(&sflag[8 + (hw ^ 1)], __ATOMIC_RELAXED, __HIP_MEMORY_SCOPE_WORKGROUP);
        if (go >= t - 2) break;
      }
      float* hp_ = &hpart[buf][hw][0];
#pragma unroll
      for (int G = 0; G < 4; ++G)
#pragma unroll
        for (int reg = 0; reg < 4; ++reg)
          hp_[G * 272 + (khi * 4 + reg) * 17 + llo] = acc[G][reg];
      asm volatile("s_waitcnt lgkmcnt(0)" ::: "memory");
      __hip_atomic_store(&sflag[4 + buf * 2 + hw], t, __ATOMIC_RELAXED, __HIP_MEMORY_SCOPE_WORKGROUP);
      // wait all 4 partials of step t (normally already set)
      for (;;){
        int f0 = __hip_atomic_load(&sflag[buf * 2],     __ATOMIC_RELAXED, __HIP_MEMORY_SCOPE_WORKGROUP);
        int f1 = __hip_atomic_load(&sflag[buf * 2 + 1], __ATOMIC_RELAXED, __HIP_MEMORY_SCOPE_WORKGROUP);
        int f2 = __hip_atomic_load(&sflag[4 + buf * 2 + (hw ^ 1)], __ATOMIC_RELAXED, __HIP_MEMORY_SCOPE_WORKGROUP);
        if (f0 >= t && f1 >= t && f2 >= t) break;
      }
      asm volatile("s_waitcnt lgkmcnt(0)" ::: "memory");
      __builtin_amdgcn_sched_barrier(0);

      // gate pre-activations in r11's exact addition order: x0 + x1 + h0 + h1 + bias
      const float* x0 = &xpart[buf][0][0];
      const float* x1 = &xpart[buf][1][0];
      const float* h0p = &hpart[buf][0][0];
      const float* h1p = &hpart[buf][1][0];
      float aG[2][4];
#pragma unroll
      for (int e = 0; e < 2; ++e)
#pragma unroll
        for (int G = 0; G < 4; ++G){
          int idx = G * 272 + r * 17 + c0 + e;
          aG[e][G] = x0[idx] + x1[idx] + h0p[idx] + h1p[idx] + bia[e][G];
        }
      asm volatile("s_waitcnt lgkmcnt(0)" ::: "memory");
      __builtin_amdgcn_sched_barrier(0);
      __hip_atomic_store(&sflag[8 + hw], t, __ATOMIC_RELAXED, __HIP_MEMORY_SCOPE_WORKGROUP);

      float hv[2]; u32 h16[2];
#pragma unroll
      for (int e = 0; e < 2; ++e){
        float gi = 1.f / (1.f + __expf(-aG[e][0]));
        float gf = 1.f / (1.f + __expf(-aG[e][1]));
        float go = 1.f / (1.f + __expf(-aG[e][2]));
        float e2 = __expf(-2.f * fabsf(aG[e][3]));
        float gg = __builtin_copysignf((1.f - e2) / (1.f + e2), aG[e][3]);
        float c  = gf * cs[e] + gi * gg;
        cs[e] = c;
        float ec = __expf(-2.f * fabsf(c));
        float th = __builtin_copysignf((1.f - ec) / (1.f + ec), c);
        hv[e] = go * th;
        h16[e] = f2bf(hv[e]);
      }
      // publish straight from the pipeline (critical path)
      u64 word = ((u64)(u32)t << 32) | ((u64)h16[1] << 16) | (u64)h16[0];
      __hip_atomic_store(gb + (size_t)(t & 3) * 4096 + swidx, word,
                         __ATOMIC_RELAXED, __HIP_MEMORY_SCOPE_AGENT);
      pend0 = hv[0]; pend1 = hv[1];
    }
    *(float2*)(outp + (size_t)(TT - 1) * HH) = make_float2(pend0, pend1);
  }
}

extern "C" void kernel_launch(void* const* d_in, const int* in_sizes, int n_in,
                              void* d_out, int out_size, void* d_ws, size_t ws_size,
                              hipStream_t stream){
  const float* x  = (const float*)d_in[0];
  const float* h0 = (const float*)d_in[1];
  const float* Wx = (const float*)d_in[2];
  const float* Wh = (const float*)d_in[3];
  const float* b  = (const float*)d_in[4];
  float* out = (float*)d_out;

  unsigned char* ws = (unsigned char*)d_ws;
  u16*   wp = (u16*)(ws + OFF_WPACK);
  uint4* xs = (uint4*)(ws + OFF_XS);
  u64*   hb = (u64*)(ws + OFF_HB);

  hipLaunchKernelGGL(k_clear,   dim3(256),   dim3(256), 0, stream, hb);
  hipLaunchKernelGGL(k_pack_w,  dim3(1024),  dim3(256), 0, stream, Wx, Wh, wp);
  hipLaunchKernelGGL(k_conv_x,  dim3(16384), dim3(256), 0, stream, x, xs);
  hipLaunchKernelGGL(k_conv_h0, dim3(64),    dim3(256), 0, stream, h0, hb);
  hipLaunchKernelGGL(k_lstm,    dim3(128),   dim3(256), 0, stream, b, out, wp, xs, hb);
}